// Round 10
// baseline (143.066 us; speedup 1.0000x reference)
//
#include <hip/hip_runtime.h>

#define NN 50000
#define NE 320000
#define FF 256
#define SCAN_B 196   // ceil(NN/256)

typedef short short8 __attribute__((ext_vector_type(8)));
typedef float f32x4 __attribute__((ext_vector_type(4)));
typedef unsigned short us4 __attribute__((ext_vector_type(4)));

static __device__ __forceinline__ unsigned short f2bf(float f) {
    union { float f; unsigned u; } v; v.f = f;
    unsigned r = v.u + 0x7FFFu + ((v.u >> 16) & 1u);   // RNE
    return (unsigned short)(r >> 16);
}
static __device__ __forceinline__ float bf2f(unsigned short h) {
    return __uint_as_float((unsigned)h << 16);
}

// ---------------- degree (int histogram over dst) ----------------
__global__ void k_deg(const int* __restrict__ ei, int* __restrict__ deg) {
    int e = blockIdx.x * blockDim.x + threadIdx.x;
    if (e < NE) atomicAdd(&deg[ei[NE + e]], 1);
}

// ---------------- hierarchical scan ----------------
__global__ void k_scan1(const int* __restrict__ deg, int* __restrict__ bsum) {
    __shared__ int s[256];
    int i = blockIdx.x * 256 + threadIdx.x;
    s[threadIdx.x] = (i < NN) ? deg[i] : 0;
    __syncthreads();
    for (int d = 128; d > 0; d >>= 1) {
        if (threadIdx.x < d) s[threadIdx.x] += s[threadIdx.x + d];
        __syncthreads();
    }
    if (threadIdx.x == 0) bsum[blockIdx.x] = s[0];
}

__global__ void k_scan2(const int* __restrict__ bsum, int* __restrict__ boff) {
    __shared__ int s[256];
    int t = threadIdx.x;
    int v = (t < SCAN_B) ? bsum[t] : 0;
    s[t] = v;
    __syncthreads();
    for (int d = 1; d < 256; d <<= 1) {
        int u = (t >= d) ? s[t - d] : 0;
        __syncthreads();
        s[t] += u;
        __syncthreads();
    }
    if (t < SCAN_B) boff[t] = s[t] - v;
}

__global__ void k_scan3(const int* __restrict__ deg, const int* __restrict__ boff,
                        int* __restrict__ off, int* __restrict__ cur,
                        float* __restrict__ dinv) {
    __shared__ int s[256];
    int t = threadIdx.x;
    int i = blockIdx.x * 256 + t;
    int v = (i < NN) ? deg[i] : 0;
    s[t] = v;
    __syncthreads();
    for (int d = 1; d < 256; d <<= 1) {
        int u = (t >= d) ? s[t - d] : 0;
        __syncthreads();
        s[t] += u;
        __syncthreads();
    }
    if (i < NN) {
        int excl = boff[blockIdx.x] + s[t] - v;
        off[i] = excl;
        cur[i] = excl;
        dinv[i] = v > 0 ? rsqrtf((float)v) : 0.f;
    }
}

// ---------------- CSR fill ----------------
__global__ void k_fill(const int* __restrict__ ei, int* __restrict__ cur,
                       int* __restrict__ csr_src) {
    int e = blockIdx.x * blockDim.x + threadIdx.x;
    if (e < NE) {
        int dst = ei[NE + e];
        int pos = atomicAdd(&cur[dst], 1);
        csr_src[pos] = ei[e];
    }
}

// ---------------- x -> bf16 x-half of Ab (swizzled rows) ----------
// Ab row byte layout: logical byte b stored at b ^ ((row&7)<<4).
__global__ void k_xcvt(const float* __restrict__ x, unsigned short* __restrict__ Ab) {
    int t = blockIdx.x * blockDim.x + threadIdx.x;
    if (t >= NN * 64) return;
    int n = t >> 6, q = t & 63;
    float4 v = *reinterpret_cast<const float4*>(&x[(size_t)n * FF + q * 4]);
    us4 o = {f2bf(v.x), f2bf(v.y), f2bf(v.z), f2bf(v.w)};
    char* rowp = (char*)(Ab + (size_t)n * 512);
    *reinterpret_cast<us4*>(rowp + ((512 + q * 8) ^ ((n & 7) << 4))) = o;
}

// ---------------- aggregation: gather BF16 x rows from Ab x-half, write y-half ------
__global__ __launch_bounds__(256)
void k_agg(const int* __restrict__ off, const int* __restrict__ deg,
           const int* __restrict__ csr_src, const float* __restrict__ dinv,
           unsigned short* __restrict__ Ab) {
    int wid = (blockIdx.x * blockDim.x + threadIdx.x) >> 6;
    if (wid >= NN) return;
    int lane = threadIdx.x & 63;
    int start = off[wid];
    int d = deg[wid];
    float di = dinv[wid];
    const char* base = (const char*)Ab;
    const int lb = 512 + lane * 8;       // logical byte offset of this lane's 4 bf16 in x-half
    float4 acc = make_float4(0.f, 0.f, 0.f, 0.f);
    int e = 0;
    for (; e + 4 <= d; e += 4) {
        int s0 = csr_src[start + e + 0];
        int s1 = csr_src[start + e + 1];
        int s2 = csr_src[start + e + 2];
        int s3 = csr_src[start + e + 3];
        us4 v0 = *reinterpret_cast<const us4*>(base + (size_t)s0 * 1024 + (lb ^ ((s0 & 7) << 4)));
        us4 v1 = *reinterpret_cast<const us4*>(base + (size_t)s1 * 1024 + (lb ^ ((s1 & 7) << 4)));
        us4 v2 = *reinterpret_cast<const us4*>(base + (size_t)s2 * 1024 + (lb ^ ((s2 & 7) << 4)));
        us4 v3 = *reinterpret_cast<const us4*>(base + (size_t)s3 * 1024 + (lb ^ ((s3 & 7) << 4)));
        float w0 = di * dinv[s0], w1 = di * dinv[s1], w2 = di * dinv[s2], w3 = di * dinv[s3];
        acc.x = fmaf(w0, bf2f(v0[0]), fmaf(w1, bf2f(v1[0]), fmaf(w2, bf2f(v2[0]), fmaf(w3, bf2f(v3[0]), acc.x))));
        acc.y = fmaf(w0, bf2f(v0[1]), fmaf(w1, bf2f(v1[1]), fmaf(w2, bf2f(v2[1]), fmaf(w3, bf2f(v3[1]), acc.y))));
        acc.z = fmaf(w0, bf2f(v0[2]), fmaf(w1, bf2f(v1[2]), fmaf(w2, bf2f(v2[2]), fmaf(w3, bf2f(v3[2]), acc.z))));
        acc.w = fmaf(w0, bf2f(v0[3]), fmaf(w1, bf2f(v1[3]), fmaf(w2, bf2f(v2[3]), fmaf(w3, bf2f(v3[3]), acc.w))));
    }
    for (; e < d; ++e) {
        int s0 = csr_src[start + e];
        us4 v0 = *reinterpret_cast<const us4*>(base + (size_t)s0 * 1024 + (lb ^ ((s0 & 7) << 4)));
        float w0 = di * dinv[s0];
        acc.x = fmaf(w0, bf2f(v0[0]), acc.x);
        acc.y = fmaf(w0, bf2f(v0[1]), acc.y);
        acc.z = fmaf(w0, bf2f(v0[2]), acc.z);
        acc.w = fmaf(w0, bf2f(v0[3]), acc.w);
    }
    char* rowp = (char*)(Ab + (size_t)wid * 512);
    us4 o = {f2bf(acc.x), f2bf(acc.y), f2bf(acc.z), f2bf(acc.w)};
    *reinterpret_cast<us4*>(rowp + ((lane * 8) ^ ((wid & 7) << 4))) = o;
}

// ---------------- B prep: fragment-linear bf16 Bp [fb = kc*32+cf][lane][8] ----------------
__global__ void k_bprep(const float* __restrict__ wi, const float* __restrict__ wr,
                        unsigned short* __restrict__ Bp) {
    int t = blockIdx.x * blockDim.x + threadIdx.x;   // 0..32767
    int l = t & 63;
    int fb = t >> 6;          // 0..511
    int kc = fb >> 5;
    int cf = fb & 31;
    int col = cf * 16 + (l & 15);
    int kpart = col >> 8;
    int g = col & 255;
    int K0 = kc * 32 + (l >> 4) * 8;
    unsigned short* dst = Bp + (size_t)fb * 512 + (size_t)l * 8;
    #pragma unroll
    for (int e = 0; e < 8; ++e) {
        int K = K0 + e;
        const float* srcp = (K < 256) ? wi : wr;
        float v = srcp[(size_t)kpart * 65536 + (size_t)(K & 255) * 256 + g];
        dst[e] = f2bf(v);
    }
}

// ---------------- MFMA GEMM + epilogue: 16 waves, dual ping-pong, wave stagger -----
// Block: 1024 threads = 16 waves, 64 rows x 512 cols.  A panel (64 KB) staged once.
// Wave w owns g-range [w*16, w*16+16) for BOTH k=0 (cf=w) and k=1 (cf=16+w).
// K-loop: wave w iterates kc = (i + w) & 15  (stagger breaks phase-lock; fp-reorder only).
// Dual register ping-pong: next {a,b} frags issued before current MFMA cluster.
#define LOADA(dst, ab, h_)                                                        \
    {                                                                             \
        _Pragma("unroll")                                                         \
        for (int rf = 0; rf < 4; ++rf)                                            \
            dst[rf] = *reinterpret_cast<const short8*>((ab) + rf * 16384 + (h_) * 128); \
    }
#define LOADB(dst, kc_)                                                           \
    {                                                                             \
        dst[0] = *reinterpret_cast<const short8*>(bpb + (kc_) * 32768 + w * 1024);        \
        dst[1] = *reinterpret_cast<const short8*>(bpb + (kc_) * 32768 + (16 + w) * 1024); \
    }
#define MFMA8(aset, bset)                                                         \
    {                                                                             \
        _Pragma("unroll")                                                         \
        for (int rf = 0; rf < 4; ++rf)                                            \
            _Pragma("unroll")                                                     \
            for (int c = 0; c < 2; ++c)                                           \
                acc[rf][c] = __builtin_amdgcn_mfma_f32_16x16x32_bf16(aset[rf], bset[c], acc[rf][c], 0, 0, 0); \
    }

__global__ __launch_bounds__(1024, 4)
void k_mm(const unsigned short* __restrict__ Ab, const unsigned short* __restrict__ Bp,
          const float* __restrict__ bias, float* __restrict__ out) {
    __shared__ char smem[65536];   // A panel, swizzled rows (1 KB each)

    const int l = threadIdx.x & 63;
    const int w = threadIdx.x >> 6;      // 0..15
    const int row0 = blockIdx.x * 64;

    // ---- stage: wave w copies rows {j*16 + w}, 1KB each via global_load_lds
    {
        const char* base = (const char*)Ab;
        #pragma unroll
        for (int j = 0; j < 4; ++j) {
            int rl = j * 16 + w;
            int rsrc = row0 + rl; if (rsrc >= NN) rsrc = NN - 1;   // clamp tail (masked later)
            const char* gp = base + (size_t)rsrc * 1024 + l * 16;
            __builtin_amdgcn_global_load_lds(
                (const __attribute__((address_space(1))) void*)gp,
                (__attribute__((address_space(3))) void*)(smem + rl * 1024),
                16, 0, 0);
        }
    }
    __syncthreads();

    f32x4 acc[4][2];                     // [row frag][c: 0=k0, 1=k1 at same g]
    #pragma unroll
    for (int i = 0; i < 4; ++i)
        #pragma unroll
        for (int j = 0; j < 2; ++j) acc[i][j] = (f32x4){0.f, 0.f, 0.f, 0.f};

    // per-lane invariant A bases. addr(rf,kc) = (l&15)*1024 + rf*16384 + (kc>>1)*128
    //   + (((kc&1)^(p>>2))<<6) + ((q^(p&3))<<4),  p=l&7, q=l>>4
    const int p = l & 7, q = l >> 4;
    const char* abaseE = smem + (l & 15) * 1024 + ((p >> 2) << 6) + ((q ^ (p & 3)) << 4);
    const char* abaseO = smem + (((size_t)(abaseE - smem)) ^ 64);
    // stagger: iteration i uses kc = (i + w) & 15; parity(kc) = parity(i+w)
    const char* abA = (w & 1) ? abaseO : abaseE;   // even i
    const char* abB = (w & 1) ? abaseE : abaseO;   // odd i
    const char* bpb = (const char*)(Bp + (size_t)l * 8);

    short8 a0[4], a1[4], b0[2], b1[2];
    {
        int kc = w;                       // i = 0
        LOADA(a0, abA, kc >> 1)
        LOADB(b0, kc)
    }
    #pragma unroll 1
    for (int i = 0; i < 14; i += 2) {
        int kcn = (i + 1 + w) & 15;
        LOADA(a1, abB, kcn >> 1)
        LOADB(b1, kcn)
        MFMA8(a0, b0)
        int kcn2 = (i + 2 + w) & 15;
        LOADA(a0, abA, kcn2 >> 1)
        LOADB(b0, kcn2)
        MFMA8(a1, b1)
    }
    {   // i = 14, 15 (no further prefetch)
        int kcn = (15 + w) & 15;
        LOADA(a1, abB, kcn >> 1)
        LOADB(b1, kcn)
        MFMA8(a0, b0)
        MFMA8(a1, b1)
    }

    // ---- epilogue: residual x read as bf16 from the LDS x-half
    const int gg = w * 16 + (l & 15);
    const float bv0 = bias[gg], bv1 = bias[256 + gg];
    #pragma unroll
    for (int rf = 0; rf < 4; ++rf) {
        const int rl0 = rf * 16 + (l >> 4) * 4;
        #pragma unroll
        for (int j = 0; j < 4; ++j) {
            int rl = rl0 + j;
            int r = row0 + rl;
            if (r >= NN) continue;
            int sw = (rl & 7) << 4;
            unsigned short xb =
                *reinterpret_cast<const unsigned short*>(&smem[rl * 1024 + ((512 + gg * 2) ^ sw)]);
            float xv = bf2f(xb);
            float c0 = acc[rf][0][j] + bv0;
            float c1 = acc[rf][1][j] + bv1;
            float arma = 0.5f * (fmaxf(c0, 0.f) + fmaxf(c1, 0.f));
            out[(size_t)r * FF + gg] = xv + fmaxf(arma, 0.f);
        }
    }
}

extern "C" void kernel_launch(void* const* d_in, const int* in_sizes, int n_in,
                              void* d_out, int out_size, void* d_ws, size_t ws_size,
                              hipStream_t stream) {
    const float* x    = (const float*)d_in[0];
    const int*   ei   = (const int*)d_in[1];
    const float* wi   = (const float*)d_in[2];
    const float* wr   = (const float*)d_in[3];
    const float* bias = (const float*)d_in[4];
    float* out = (float*)d_out;

    // workspace (~2.6 MB)
    int*   deg     = (int*)d_ws;              // NN
    int*   off     = deg + NN;                // NN
    int*   cur     = off + NN;                // NN
    int*   csr_src = cur + NN;                // NE
    float* dinv    = (float*)(csr_src + NE);  // NN
    int*   bsum    = (int*)(dinv + NN);       // SCAN_B
    int*   boff    = bsum + SCAN_B;           // SCAN_B
    unsigned short* Bp = (unsigned short*)(boff + SCAN_B);   // 512*512 bf16 = 512 KB
    unsigned short* Ab = (unsigned short*)d_out;             // 50000 x 512 bf16 == d_out bytes

    hipMemsetAsync(deg, 0, NN * sizeof(int), stream);

    k_deg  <<<(NE + 255) / 256, 256, 0, stream>>>(ei, deg);
    k_scan1<<<SCAN_B, 256, 0, stream>>>(deg, bsum);
    k_scan2<<<1, 256, 0, stream>>>(bsum, boff);
    k_scan3<<<SCAN_B, 256, 0, stream>>>(deg, boff, off, cur, dinv);
    k_fill <<<(NE + 255) / 256, 256, 0, stream>>>(ei, cur, csr_src);
    k_xcvt <<<(NN * 64 + 255) / 256, 256, 0, stream>>>(x, Ab);
    k_bprep<<<128, 256, 0, stream>>>(wi, wr, Bp);
    k_agg  <<<(NN * 64 + 255) / 256, 256, 0, stream>>>(off, deg, csr_src, dinv, Ab);
    k_mm   <<<(NN + 63) / 64, 1024, 0, stream>>>(Ab, Bp, bias, out);
}